// Round 3
// baseline (1110.921 us; speedup 1.0000x reference)
//
#include <hip/hip_runtime.h>
#include <hip/hip_bf16.h>

using f32x4  = __attribute__((ext_vector_type(4))) float;
using bf16x8 = __attribute__((ext_vector_type(8))) short;
using short8 = __attribute__((ext_vector_type(8))) short;

#define DEVINL __device__ __forceinline__

DEVINL short f2bf(float f) {
  unsigned u = __builtin_bit_cast(unsigned, f);
  u += 0x7fffu + ((u >> 16) & 1u);          // RNE
  return (short)(u >> 16);
}

#define GLDS16(g, l) __builtin_amdgcn_global_load_lds( \
    (const __attribute__((address_space(1))) void*)(g), \
    (__attribute__((address_space(3))) void*)(l), 16, 0, 0)

// ---------------------------------------------------------------- transpose
// out[c*R + r] = in[r*C + c]  (fp32 -> bf16), builds B^T weight layouts
__global__ __launch_bounds__(256)
void transpose_bf16(const float* __restrict__ in, short* __restrict__ out, int R, int C) {
  int idx = blockIdx.x * 256 + threadIdx.x;
  if (idx >= R * C) return;
  int c = idx / R, r = idx % R;
  out[idx] = f2bf(in[(size_t)r * C + c]);
}

// ---------------------------------------------------------------- bias expand
// BIASF[head][n][m] = rpb[rpi(n,m)][head]   (16x64x64 f32 = 256KB, L2-hot)
__global__ __launch_bounds__(256)
void bias_expand(const float* __restrict__ rpb, float* __restrict__ BIASF) {
  int idx = blockIdx.x * 256 + threadIdx.x;   // 65536
  int head = idx >> 12, n = (idx >> 6) & 63, m = idx & 63;
  int i1 = n >> 3, j1 = n & 7, i2 = m >> 3, j2 = m & 7;
  BIASF[idx] = rpb[((i1 - i2 + 7) * 15 + (j1 - j2 + 7)) * 16 + head];
}

// ---------------------------------------------------------------- LayerNorm
// one wave per token (64 lanes x 8 ch = 512). REMAP=1: shift+window-partition dest.
template<int REMAP>
__global__ __launch_bounds__(256)
void ln_kernel(const float* __restrict__ X, const float* __restrict__ gamma,
               const float* __restrict__ beta, short* __restrict__ OUT) {
  const int lane = threadIdx.x & 63;
  const int wid  = threadIdx.x >> 6;
  const int t    = blockIdx.x * 4 + wid;
  const float* xp = X + (size_t)t * 512 + lane * 8;
  float4 a = *(const float4*)xp;
  float4 b = *(const float4*)(xp + 4);
  float s = a.x + a.y + a.z + a.w + b.x + b.y + b.z + b.w;
  float q = a.x*a.x + a.y*a.y + a.z*a.z + a.w*a.w
          + b.x*b.x + b.y*b.y + b.z*b.z + b.w*b.w;
#pragma unroll
  for (int d = 1; d < 64; d <<= 1) { s += __shfl_xor(s, d); q += __shfl_xor(q, d); }
  float mean = s * (1.0f / 512.0f);
  float var  = q * (1.0f / 512.0f) - mean * mean;
  float rstd = rsqrtf(var + 1e-5f);
  float4 g0 = *(const float4*)(gamma + lane * 8);
  float4 g1 = *(const float4*)(gamma + lane * 8 + 4);
  float4 b0 = *(const float4*)(beta + lane * 8);
  float4 b1 = *(const float4*)(beta + lane * 8 + 4);
  short8 o;
  o[0] = f2bf((a.x - mean) * rstd * g0.x + b0.x);
  o[1] = f2bf((a.y - mean) * rstd * g0.y + b0.y);
  o[2] = f2bf((a.z - mean) * rstd * g0.z + b0.z);
  o[3] = f2bf((a.w - mean) * rstd * g0.w + b0.w);
  o[4] = f2bf((b.x - mean) * rstd * g1.x + b1.x);
  o[5] = f2bf((b.y - mean) * rstd * g1.y + b1.y);
  o[6] = f2bf((b.z - mean) * rstd * g1.z + b1.z);
  o[7] = f2bf((b.w - mean) * rstd * g1.w + b1.w);
  size_t orow;
  if (REMAP) {
    int bb = t >> 12, l = t & 4095, hh = l >> 6, ww = l & 63;
    int hs = (hh + 60) & 63, ws2 = (ww + 60) & 63;   // (coord - 4) mod 64
    orow = (size_t)(bb * 64 + (hs >> 3) * 8 + (ws2 >> 3)) * 64 + (hs & 7) * 8 + (ws2 & 7);
  } else {
    orow = (size_t)t;
  }
  *(short8*)(OUT + orow * 512 + lane * 8) = o;
}

// ---------------------------------------------------------------- attention core
// one wave = one (window, head). LDS: per-wave P[64][64] bf16, XOR-swizzled.
__global__ __launch_bounds__(256)
void attn_core(const short* __restrict__ Q, const short* __restrict__ Kb,
               const short* __restrict__ VT, const float* __restrict__ BIASF,
               short* __restrict__ AOUT) {
  __shared__ short P[4][4096];
  const int tid = threadIdx.x, lane = tid & 63, wid = tid >> 6;
  const int lr = lane & 15, lg = lane >> 4;
  const int gw = blockIdx.x * 4 + wid;
  const int win = gw >> 4, head = gw & 15;
  const int wimg = win & 63, wh = wimg >> 3, ww = wimg & 7;
  const size_t qbase = (size_t)win * 64 * 512 + head * 32;
  short* Pb = P[wid];

  // ---- S = q k^T (scale pre-folded into Q)
  bf16x8 aq[4], bk[4];
#pragma unroll
  for (int tm = 0; tm < 4; ++tm) aq[tm] = *(const bf16x8*)(Q  + qbase + (size_t)(tm * 16 + lr) * 512 + lg * 8);
#pragma unroll
  for (int tn = 0; tn < 4; ++tn) bk[tn] = *(const bf16x8*)(Kb + qbase + (size_t)(tn * 16 + lr) * 512 + lg * 8);
  f32x4 sa[4][4] = {};
#pragma unroll
  for (int tm = 0; tm < 4; ++tm)
#pragma unroll
    for (int tn = 0; tn < 4; ++tn)
      sa[tm][tn] = __builtin_amdgcn_mfma_f32_16x16x32_bf16(aq[tm], bk[tn], sa[tm][tn], 0, 0, 0);

  // ---- softmax (rows n = tm*16+lg*4+e; cols m = tn*16+lr), 1/sum deferred
  const float* bias_h = BIASF + head * 4096;
  float inv[4][4];
#pragma unroll
  for (int tm = 0; tm < 4; ++tm) {
#pragma unroll
    for (int e = 0; e < 4; ++e) {
      const int n = tm * 16 + lg * 4 + e;
      const int i1 = n >> 3, j1 = n & 7;
      const int rh1 = (wh == 7) ? 1 + (i1 >> 2) : 0;
      const int rw1 = (ww == 7) ? 1 + (j1 >> 2) : 0;
      float v[4];
      float mx = -3.0e38f;
#pragma unroll
      for (int tn = 0; tn < 4; ++tn) {
        const int m = tn * 16 + lr;
        const int mi = (m >> 3), mj = m & 7;
        const int rh2 = (wh == 7) ? 1 + (mi >> 2) : 0;
        const int rw2 = (ww == 7) ? 1 + (mj >> 2) : 0;
        float val = sa[tm][tn][e] + bias_h[n * 64 + m]
                  + ((rh1 != rh2 || rw1 != rw2) ? -100.0f : 0.0f);
        v[tn] = val;
        mx = fmaxf(mx, val);
      }
#pragma unroll
      for (int d = 1; d < 16; d <<= 1) mx = fmaxf(mx, __shfl_xor(mx, d));
      float sum = 0.f;
#pragma unroll
      for (int tn = 0; tn < 4; ++tn) { v[tn] = __expf(v[tn] - mx); sum += v[tn]; }
#pragma unroll
      for (int d = 1; d < 16; d <<= 1) sum += __shfl_xor(sum, d);
      inv[tm][e] = 1.0f / sum;
      const int sw = (n & 7) << 3;
#pragma unroll
      for (int tn = 0; tn < 4; ++tn) Pb[n * 64 + ((tn * 16 + lr) ^ sw)] = f2bf(v[tn]);
    }
  }
  __syncthreads();

  // ---- O = P @ V  (B from VT[win][head][d][n], contiguous global loads)
  f32x4 oa[4][2] = {};
  const short* vt = VT + (size_t)win * 32768 + head * 2048;
#pragma unroll
  for (int ks = 0; ks < 2; ++ks) {
    bf16x8 pa[4], bv[2];
#pragma unroll
    for (int tm = 0; tm < 4; ++tm) {
      const int r = tm * 16 + lr;
      pa[tm] = *(const bf16x8*)(Pb + r * 64 + ((ks * 32 + lg * 8) ^ ((r & 7) << 3)));
    }
#pragma unroll
    for (int t2 = 0; t2 < 2; ++t2) bv[t2] = *(const bf16x8*)(vt + (t2 * 16 + lr) * 64 + ks * 32 + lg * 8);
#pragma unroll
    for (int tm = 0; tm < 4; ++tm)
#pragma unroll
      for (int t2 = 0; t2 < 2; ++t2)
        oa[tm][t2] = __builtin_amdgcn_mfma_f32_16x16x32_bf16(pa[tm], bv[t2], oa[tm][t2], 0, 0, 0);
  }
#pragma unroll
  for (int tm = 0; tm < 4; ++tm)
#pragma unroll
    for (int t2 = 0; t2 < 2; ++t2)
#pragma unroll
      for (int e = 0; e < 4; ++e) {
        const int n = tm * 16 + lg * 4 + e;
        AOUT[((size_t)win * 64 + n) * 512 + head * 32 + t2 * 16 + lr] = f2bf(oa[tm][t2][e] * inv[tm][e]);
      }
}

// ---------------------------------------------------------------- fused MLP
// out = X2 + fc2(gelu(fc1(ln(X2)))).  Block = 64 rows, 8 waves, wave owns 64 out cols.
// LDS: A[64][512] bf16 (LN'd rows, XOR-swizzled) + Hs[64][128] bf16 (H chunk).
// W1T [2048][512], W2T [512][2048] read as register B-frags from global (L2/L3-hot).
__global__ __launch_bounds__(512, 2)
void mlp_fused(const float* __restrict__ X2, const float* __restrict__ g2,
               const float* __restrict__ b2,
               const short* __restrict__ W1T, const float* __restrict__ fb1,
               const short* __restrict__ W2T, const float* __restrict__ fb2,
               float* __restrict__ out) {
  __shared__ short A[64 * 512];    // 64 KB
  __shared__ short Hs[64 * 128];   // 16 KB
  const int tid = threadIdx.x, lane = tid & 63, w = tid >> 6;
  const int lr = lane & 15, lg = lane >> 4;
  const int m0 = blockIdx.x * 64;

  // ---- LN staging: wave w normalizes rows w*8 .. w*8+7 into A (swizzled)
  {
    float4 gg0 = *(const float4*)(g2 + lane * 8);
    float4 gg1 = *(const float4*)(g2 + lane * 8 + 4);
    float4 bb0 = *(const float4*)(b2 + lane * 8);
    float4 bb1 = *(const float4*)(b2 + lane * 8 + 4);
    for (int rr = 0; rr < 8; ++rr) {
      const int r = w * 8 + rr;
      const float* xp = X2 + (size_t)(m0 + r) * 512 + lane * 8;
      float4 a = *(const float4*)xp;
      float4 b = *(const float4*)(xp + 4);
      float s = a.x + a.y + a.z + a.w + b.x + b.y + b.z + b.w;
      float q = a.x*a.x + a.y*a.y + a.z*a.z + a.w*a.w
              + b.x*b.x + b.y*b.y + b.z*b.z + b.w*b.w;
#pragma unroll
      for (int d = 1; d < 64; d <<= 1) { s += __shfl_xor(s, d); q += __shfl_xor(q, d); }
      float mean = s * (1.0f / 512.0f);
      float var  = q * (1.0f / 512.0f) - mean * mean;
      float rstd = rsqrtf(var + 1e-5f);
      short8 o;
      o[0] = f2bf((a.x - mean) * rstd * gg0.x + bb0.x);
      o[1] = f2bf((a.y - mean) * rstd * gg0.y + bb0.y);
      o[2] = f2bf((a.z - mean) * rstd * gg0.z + bb0.z);
      o[3] = f2bf((a.w - mean) * rstd * gg0.w + bb0.w);
      o[4] = f2bf((b.x - mean) * rstd * gg1.x + bb1.x);
      o[5] = f2bf((b.y - mean) * rstd * gg1.y + bb1.y);
      o[6] = f2bf((b.z - mean) * rstd * gg1.z + bb1.z);
      o[7] = f2bf((b.w - mean) * rstd * gg1.w + bb1.w);
      *(short8*)((char*)A + ((r * 1024 + lane * 16) ^ ((r & 7) << 4))) = o;
    }
  }
  __syncthreads();

  f32x4 acc2[4][4] = {};           // 64 rows x 64 cols (w*64 ..)
  for (int hc = 0; hc < 16; ++hc) {
    // ---- H chunk: wave computes H[0:64][hc*128 + w*16 + lr]
    f32x4 acch[4] = {};
    const short* w1p = W1T + (size_t)(hc * 128 + w * 16 + lr) * 512 + lg * 8;
#pragma unroll
    for (int kk = 0; kk < 16; ++kk) {
      bf16x8 bfrag = *(const bf16x8*)(w1p + kk * 32);
      bf16x8 afr[4];
#pragma unroll
      for (int i = 0; i < 4; ++i) {
        const int row = i * 16 + lr;
        afr[i] = *(const bf16x8*)((const char*)A + ((row * 1024 + kk * 64 + lg * 16) ^ ((row & 7) << 4)));
      }
#pragma unroll
      for (int i = 0; i < 4; ++i)
        acch[i] = __builtin_amdgcn_mfma_f32_16x16x32_bf16(afr[i], bfrag, acch[i], 0, 0, 0);
    }
    const float hb = fb1[hc * 128 + w * 16 + lr];
    __syncthreads();               // previous fc2-phase reads of Hs complete
#pragma unroll
    for (int i = 0; i < 4; ++i)
#pragma unroll
      for (int e = 0; e < 4; ++e) {
        const int row = i * 16 + lg * 4 + e;
        float v = acch[i][e] + hb;
        float g = 0.5f * v * (1.0f + erff(v * 0.70710678118654752f));
        *(short*)((char*)Hs + ((row * 256 + (w * 16 + lr) * 2) ^ ((row & 7) << 4))) = f2bf(g);
      }
    __syncthreads();
    // ---- fc2 partial: K = 128
#pragma unroll
    for (int ks = 0; ks < 4; ++ks) {
      bf16x8 ha[4], wb[4];
#pragma unroll
      for (int i = 0; i < 4; ++i) {
        const int row = i * 16 + lr;
        ha[i] = *(const bf16x8*)((const char*)Hs + ((row * 256 + ks * 64 + lg * 16) ^ ((row & 7) << 4)));
      }
#pragma unroll
      for (int j = 0; j < 4; ++j)
        wb[j] = *(const bf16x8*)(W2T + (size_t)(w * 64 + j * 16 + lr) * 2048 + hc * 128 + ks * 32 + lg * 8);
#pragma unroll
      for (int i = 0; i < 4; ++i)
#pragma unroll
        for (int j = 0; j < 4; ++j)
          acc2[i][j] = __builtin_amdgcn_mfma_f32_16x16x32_bf16(ha[i], wb[j], acc2[i][j], 0, 0, 0);
    }
  }
  // ---- epilogue: + fc2 bias + residual
#pragma unroll
  for (int j = 0; j < 4; ++j) {
    const int col = w * 64 + j * 16 + lr;
    const float bc = fb2[col];
#pragma unroll
    for (int i = 0; i < 4; ++i)
#pragma unroll
      for (int e = 0; e < 4; ++e) {
        const int row = m0 + i * 16 + lg * 4 + e;
        out[(size_t)row * 512 + col] = acc2[i][j][e] + bc + X2[(size_t)row * 512 + col];
      }
  }
}

// ---------------------------------------------------------------- 128x128 GEMM (m97 structure)
// EPI 0: proj  -> X2 fp32 at window-reversed+unshifted row, + x residual + bias
// EPI 3: qkv   -> outh: Q (scaled) | K | VT[win][head][d][n], all bf16
template<int EPI>
__global__ __launch_bounds__(256, 2)
void gemm128(const short* __restrict__ A, const short* __restrict__ BT,
             const int N, const int K,
             const float* __restrict__ bias,
             const float* __restrict__ resid,
             float* __restrict__ outf, short* __restrict__ outh) {
  __shared__ short As[128 * 32];
  __shared__ short Bs[128 * 32];
  const int tid = threadIdx.x, lane = tid & 63, wid = tid >> 6;
  const int lr = lane & 15, lg = lane >> 4;
  const int wm = wid >> 1, wn = wid & 1;
  const int m0 = blockIdx.y * 128, n0 = blockIdx.x * 128;
  const int srow = lane >> 2;            // 0..15
  const int scol = (lane & 3) * 8;       // 0,8,16,24
  f32x4 acc[4][4] = {};
  for (int kt = 0; kt < K; kt += 32) {
#pragma unroll
    for (int c = 0; c < 2; ++c) {
      const int chunk = wid * 2 + c;     // 0..7, 16 rows each
      GLDS16(A  + (size_t)(m0 + chunk * 16 + srow) * K + kt + scol, As + chunk * 512);
      GLDS16(BT + (size_t)(n0 + chunk * 16 + srow) * K + kt + scol, Bs + chunk * 512);
    }
    __syncthreads();
    bf16x8 af[4], bf_[4];
#pragma unroll
    for (int t = 0; t < 4; ++t) af[t]  = *(const bf16x8*)(As + (wm * 64 + t * 16 + lr) * 32 + lg * 8);
#pragma unroll
    for (int t = 0; t < 4; ++t) bf_[t] = *(const bf16x8*)(Bs + (wn * 64 + t * 16 + lr) * 32 + lg * 8);
#pragma unroll
    for (int i = 0; i < 4; ++i)
#pragma unroll
      for (int j = 0; j < 4; ++j)
        acc[i][j] = __builtin_amdgcn_mfma_f32_16x16x32_bf16(af[i], bf_[j], acc[i][j], 0, 0, 0);
    __syncthreads();
  }
#pragma unroll
  for (int j = 0; j < 4; ++j) {
    const int col = n0 + wn * 64 + j * 16 + lr;
    const float bc = bias[col];
#pragma unroll
    for (int i = 0; i < 4; ++i)
#pragma unroll
      for (int e = 0; e < 4; ++e) {
        const int row = m0 + wm * 64 + i * 16 + lg * 4 + e;
        float v = acc[i][j][e] + bc;
        if (EPI == 0) {
          const int w = row >> 6, n = row & 63;
          const int bb = w >> 6, wi = w & 63;
          const int hs = (wi >> 3) * 8 + (n >> 3), ws2 = (wi & 7) * 8 + (n & 7);
          const int hh = (hs + 4) & 63, wwp = (ws2 + 4) & 63;
          const size_t orow = (size_t)bb * 4096 + hh * 64 + wwp;
          outf[orow * 512 + col] = resid[orow * 512 + col] + v;
        } else {
          // QKV epilogue: seg uniform per block (n0 multiple of 128 within 512-col segs)
          const int seg = col >> 9;
          if (seg == 0) {
            outh[(size_t)row * 512 + col] = f2bf(v * 0.17677669529663687f);  // Q * 1/sqrt(32)
          } else if (seg == 1) {
            outh[33554432 + (size_t)row * 512 + (col - 512)] = f2bf(v);      // K
          } else {
            const int cc = col - 1024;                                        // V^T
            outh[67108864 + (size_t)((row >> 6) * 16 + (cc >> 5)) * 2048 + (cc & 31) * 64 + (row & 63)] = f2bf(v);
          }
        }
      }
  }
}

// ---------------------------------------------------------------- launch
extern "C" void kernel_launch(void* const* d_in, const int* in_sizes, int n_in,
                              void* d_out, int out_size, void* d_ws, size_t ws_size,
                              hipStream_t stream) {
  (void)in_sizes; (void)n_in; (void)out_size; (void)ws_size;
  const float* x      = (const float*)d_in[0];
  const float* g1     = (const float*)d_in[1];
  const float* b1     = (const float*)d_in[2];
  const float* qkv_w  = (const float*)d_in[3];
  const float* qkv_b  = (const float*)d_in[4];
  const float* proj_w = (const float*)d_in[5];
  const float* proj_b = (const float*)d_in[6];
  const float* rpb    = (const float*)d_in[7];
  const float* g2     = (const float*)d_in[8];
  const float* b2     = (const float*)d_in[9];
  const float* fc1_w  = (const float*)d_in[10];
  const float* fc1_b  = (const float*)d_in[11];
  const float* fc2_w  = (const float*)d_in[12];
  const float* fc2_b  = (const float*)d_in[13];
  float* out = (float*)d_out;
  char* ws = (char*)d_ws;

  short* WQKVT  = (short*)(ws);                 // [1536][512] bf16   1.5MB
  short* WPROJT = (short*)(ws + 1572864);       // [512][512]         0.5MB
  short* WFC1T  = (short*)(ws + 2097152);       // [2048][512]        2MB
  short* WFC2T  = (short*)(ws + 4194304);       // [512][2048]        2MB
  float* X2     = (float*)(ws + 6291456);       // [65536][512] fp32  134MB
  float* BIASF  = (float*)(ws + 6291456);       // 256KB, aliases X2 head (dead before proj writes X2)
  short* ATT    = (short*)(ws + 140509184);     // [65536][512] bf16  64MB
  short* XW     = (short*)(ws + 207618048);     // [65536][512] bf16  64MB
  short* QB     = (short*)(ws + 274726912);     // Q|K|VT 3x64MB

  transpose_bf16<<<3072, 256, 0, stream>>>(qkv_w,  WQKVT, 512, 1536);
  transpose_bf16<<<1024, 256, 0, stream>>>(proj_w, WPROJT, 512, 512);
  transpose_bf16<<<4096, 256, 0, stream>>>(fc1_w,  WFC1T, 512, 2048);
  transpose_bf16<<<4096, 256, 0, stream>>>(fc2_w,  WFC2T, 2048, 512);
  bias_expand<<<256, 256, 0, stream>>>(rpb, BIASF);

  ln_kernel<1><<<16384, 256, 0, stream>>>(x, g1, b1, XW);
  gemm128<3><<<dim3(12, 512), 256, 0, stream>>>(XW, WQKVT, 1536, 512, qkv_b, nullptr, nullptr, QB);
  attn_core<<<4096, 256, 0, stream>>>(QB, QB + 33554432, QB + 67108864, BIASF, ATT);
  gemm128<0><<<dim3(4, 512), 256, 0, stream>>>(ATT, WPROJT, 512, 512, proj_b, x, X2, nullptr);
  mlp_fused<<<1024, 512, 0, stream>>>(X2, g2, b2, WFC1T, fc1_b, WFC2T, fc2_b, out);
}